// Round 14
// baseline (368.491 us; speedup 1.0000x reference)
//
#include <hip/hip_runtime.h>
#include <hip/hip_bf16.h>
#include <math.h>

// MEASUREMENT ROUND: exact 84.8us best-known source, but sim_mfma_kernel
// re-computes its (identical) result SIM_REP times so its single dispatch
// (~8x S) tops the rocprof table and finally exposes sim's counters.
#define SIM_REP 8

// Problem constants (match reference)
#define BB      8
#define C_CH    128
#define HH      256
#define WW      256
#define N_POS   2048
#define N_NEG   8192
#define N_ROWS  (N_POS + N_NEG)     // 10240
#define EPS_N   1e-6f

// sim tiling: block = 4 waves as 2x2, each wave 64x64 output, K=128 in 4 steps
#define NIB     (N_POS / 128)       // 16
#define NJB     (N_ROWS / 128)      // 80
#define NJSLAB      (N_ROWS / 64)   // 160 j-slabs of 64 cols (per-wave extent)
#define NJSLAB_POS  (N_POS / 64)    // 32

typedef __attribute__((ext_vector_type(8))) short bf16x8;   // 8 bf16 = 4 VGPR
typedef __attribute__((ext_vector_type(4))) float f32x4;    // MFMA C/D

// Workspace layout:
//   hi:      [N_ROWS][128] bf16   @ 0              (2.62 MB)
//   lo:      [N_ROWS][128] bf16   @ 2.62 MB        (2.62 MB)
//   partial: [NJSLAB][N_POS] f32                   (1.31 MB)
//   bsum:    [8] f32                               (32 B)

// ---------------------------------------------------------------------------
// Kernel 1: gather + L2-normalize + split to bf16 hi/lo. 1 row/wave (measured:
// G+launch ~= 25 us, r10 probe). Lane l owns channels l and l+64.
__global__ __launch_bounds__(256) void gather_norm_kernel(
    const float* __restrict__ seg,
    const int* __restrict__ pb, const int* __restrict__ ph, const int* __restrict__ pw,
    const int* __restrict__ nb, const int* __restrict__ nh, const int* __restrict__ nw,
    __hip_bfloat16* __restrict__ hi, __hip_bfloat16* __restrict__ lo)
{
    const int wave = threadIdx.x >> 6;
    const int lane = threadIdx.x & 63;
    const int row  = blockIdx.x * 4 + wave;
    if (row >= N_ROWS) return;

    int b, h, w;
    if (row < N_POS) { b = pb[row]; h = ph[row]; w = pw[row]; }
    else { const int r = row - N_POS; b = nb[r]; h = nh[r]; w = nw[r]; }

    const size_t cs   = (size_t)HH * WW;
    const size_t base = (size_t)b * C_CH * cs + (size_t)h * WW + (size_t)w;

    const float v0 = seg[base + (size_t)lane * cs];
    const float v1 = seg[base + (size_t)(lane + 64) * cs];

    float ss = v0 * v0 + v1 * v1;
#pragma unroll
    for (int m = 1; m < 64; m <<= 1) ss += __shfl_xor(ss, m, 64);

    const float n  = fmaxf(sqrtf(ss), EPS_N);
    const float u0 = v0 / n;
    const float u1 = v1 / n;

    const __hip_bfloat16 h0 = __float2bfloat16(u0);
    const __hip_bfloat16 h1 = __float2bfloat16(u1);
    const __hip_bfloat16 l0 = __float2bfloat16(u0 - __bfloat162float(h0));
    const __hip_bfloat16 l1 = __float2bfloat16(u1 - __bfloat162float(h1));

    const size_t o = (size_t)row * C_CH + lane;
    hi[o]      = h0;  lo[o]      = l0;
    hi[o + 64] = h1;  lo[o + 64] = l1;
}

// ---------------------------------------------------------------------------
// Kernel 2: C[i][j] = dot(x_i, x_j) via 3-term split-bf16 MFMA, no LDS
// (operands L2/L3-resident). Body identical to the 84.8us source; repeated
// SIM_REP times (idempotent) for counter visibility.
__global__ __launch_bounds__(256, 2) void sim_mfma_kernel(
    const __hip_bfloat16* __restrict__ hi_, const __hip_bfloat16* __restrict__ lo_,
    float* __restrict__ partial)
{
    const ushort* __restrict__ hi = (const ushort*)hi_;
    const ushort* __restrict__ lo = (const ushort*)lo_;

    const int bid = blockIdx.x;
    const int ib  = bid / NJB;          // 0..15
    const int jb  = bid % NJB;          // 0..79  (ids sharing jb are == mod 8 -> same XCD)
    const int t    = threadIdx.x;
    const int wave = t >> 6;
    const int lane = t & 63;
    const int wy = wave >> 1;           // i-half
    const int wx = wave & 1;            // j-half

    const int iw0 = ib * 128 + wy * 64;
    const int jw0 = jb * 128 + wx * 64;

    const int lr = lane & 15;           // row/col within 16x16 tile
    const int lk = lane >> 4;           // k-chunk (8 bf16)

    for (int rep = 0; rep < SIM_REP; ++rep) {
        asm volatile("" ::: "memory");   // keep each rep's loads/stores live

        f32x4 acc[4][4];
#pragma unroll
        for (int m = 0; m < 4; ++m)
#pragma unroll
            for (int n = 0; n < 4; ++n) acc[m][n] = (f32x4){0.f, 0.f, 0.f, 0.f};

#pragma unroll
        for (int ks = 0; ks < 4; ++ks) {
            const int koff = ks * 32 + lk * 8;

            bf16x8 ah[4], al[4];
#pragma unroll
            for (int m = 0; m < 4; ++m) {
                const size_t ra = (size_t)(iw0 + m * 16 + lr) * C_CH + koff;
                ah[m] = *(const bf16x8*)&hi[ra];
                al[m] = *(const bf16x8*)&lo[ra];
            }
#pragma unroll
            for (int n = 0; n < 4; ++n) {
                const size_t rb = (size_t)(jw0 + n * 16 + lr) * C_CH + koff;
                const bf16x8 bh = *(const bf16x8*)&hi[rb];
                const bf16x8 bl = *(const bf16x8*)&lo[rb];
#pragma unroll
                for (int m = 0; m < 4; ++m) {
                    acc[m][n] = __builtin_amdgcn_mfma_f32_16x16x32_bf16(ah[m], bh, acc[m][n], 0, 0, 0);
                    acc[m][n] = __builtin_amdgcn_mfma_f32_16x16x32_bf16(ah[m], bl, acc[m][n], 0, 0, 0);
                    acc[m][n] = __builtin_amdgcn_mfma_f32_16x16x32_bf16(al[m], bh, acc[m][n], 0, 0, 0);
                }
            }
        }

        // Epilogue. value r of lane l = C[iw0+m*16+(l>>4)*4+r][jw0+n*16+(l&15)]
        const int jslab = jw0 >> 6;         // 0..159
#pragma unroll
        for (int m = 0; m < 4; ++m) {
            float s0 = 0.f, s1 = 0.f, s2 = 0.f, s3 = 0.f;
#pragma unroll
            for (int n = 0; n < 4; ++n) {
                s0 += expf(acc[m][n][0]);
                s1 += expf(acc[m][n][1]);
                s2 += expf(acc[m][n][2]);
                s3 += expf(acc[m][n][3]);
            }
            float s[4] = {s0, s1, s2, s3};
#pragma unroll
            for (int r = 0; r < 4; ++r) {
                float v = s[r];
                v += __shfl_xor(v, 1, 64);
                v += __shfl_xor(v, 2, 64);
                v += __shfl_xor(v, 4, 64);
                v += __shfl_xor(v, 8, 64);
                if (lr == 0) {
                    const int row = iw0 + m * 16 + lk * 4 + r;
                    partial[(size_t)jslab * N_POS + row] = v;
                }
            }
        }
    }
}

// ---------------------------------------------------------------------------
// Kernel 3a: per-row reduction + in-block sum (r11 form).
__global__ __launch_bounds__(256) void rowred_kernel(
    const float* __restrict__ partial, float* __restrict__ bsum)
{
    const int t   = threadIdx.x;
    const int row = blockIdx.x * 256 + t;

    float P = 0.f;
#pragma unroll
    for (int s = 0; s < NJSLAB_POS; ++s) P += partial[(size_t)s * N_POS + row];

    float a0 = 0.f, a1 = 0.f, a2 = 0.f, a3 = 0.f;
    for (int s0 = NJSLAB_POS; s0 < NJSLAB; s0 += 16) {
        float v[16];
#pragma unroll
        for (int i = 0; i < 16; ++i)
            v[i] = partial[(size_t)(s0 + i) * N_POS + row];
#pragma unroll
        for (int i = 0; i < 16; i += 4) {
            a0 += v[i]; a1 += v[i + 1]; a2 += v[i + 2]; a3 += v[i + 3];
        }
    }
    const float Nv = (a0 + a1) + (a2 + a3);

    const float p = P - 2.71828182845904523536f;   // remove self-sim exp(1)
    const float term = logf(p) - logf(p + Nv);

    __shared__ float red[256];
    red[t] = term;
    __syncthreads();
    for (int s = 128; s > 0; s >>= 1) {
        if (t < s) red[t] += red[t + s];
        __syncthreads();
    }
    if (t == 0) bsum[blockIdx.x] = red[0];
}

// Kernel 3b: sum the 8 block sums. Single wave, deterministic.
__global__ __launch_bounds__(64) void final_kernel(
    const float* __restrict__ bsum, float* __restrict__ out)
{
    if (threadIdx.x == 0) {
        float s = 0.f;
#pragma unroll
        for (int i = 0; i < N_POS / 256; ++i) s += bsum[i];
        out[0] = -s / (float)N_POS;
    }
}

// ---------------------------------------------------------------------------
extern "C" void kernel_launch(void* const* d_in, const int* in_sizes, int n_in,
                              void* d_out, int out_size, void* d_ws, size_t ws_size,
                              hipStream_t stream)
{
    const float* seg = (const float*)d_in[0];
    const int* pb = (const int*)d_in[1];
    const int* ph = (const int*)d_in[2];
    const int* pw = (const int*)d_in[3];
    const int* nb = (const int*)d_in[4];
    const int* nh = (const int*)d_in[5];
    const int* nw = (const int*)d_in[6];
    float* out = (float*)d_out;

    __hip_bfloat16* hi = (__hip_bfloat16*)d_ws;
    __hip_bfloat16* lo = hi + (size_t)N_ROWS * C_CH;
    float* partial = (float*)(lo + (size_t)N_ROWS * C_CH);
    float* bsum    = partial + (size_t)NJSLAB * N_POS;

    gather_norm_kernel<<<dim3((N_ROWS + 3) / 4), dim3(256), 0, stream>>>(
        seg, pb, ph, pw, nb, nh, nw, hi, lo);

    sim_mfma_kernel<<<dim3(NIB * NJB), dim3(256), 0, stream>>>(hi, lo, partial);

    rowred_kernel<<<dim3(N_POS / 256), dim3(256), 0, stream>>>(partial, bsum);
    final_kernel<<<dim3(1), dim3(64), 0, stream>>>(bsum, out);
}

// Round 15
// 83.698 us; speedup vs baseline: 4.4026x; 4.4026x over previous
//
#include <hip/hip_runtime.h>
#include <hip/hip_bf16.h>
#include <math.h>

// Problem constants (match reference)
#define BB      8
#define C_CH    128
#define HH      256
#define WW      256
#define N_POS   2048
#define N_NEG   8192
#define N_ROWS  (N_POS + N_NEG)     // 10240
#define EPS_N   1e-6f

// sim tiling: block = 4 waves as 2x2, each wave 64x64 output, K=128 in 4 steps
#define NIB     (N_POS / 128)       // 16
#define NJB     (N_ROWS / 128)      // 80
#define NJSLAB      (N_ROWS / 64)   // 160 j-slabs of 64 cols (per-wave extent)
#define NJSLAB_POS  (N_POS / 64)    // 32

typedef __attribute__((ext_vector_type(8))) short bf16x8;   // 8 bf16 = 4 VGPR
typedef __attribute__((ext_vector_type(4))) float f32x4;    // MFMA C/D

// Workspace layout:
//   hi:      [N_ROWS][128] bf16   @ 0              (2.62 MB)
//   lo:      [N_ROWS][128] bf16   @ 2.62 MB        (2.62 MB)
//   partial: [NJSLAB][N_POS] f32                   (1.31 MB)
//   bsum:    [8] f32                               (32 B)

// ---------------------------------------------------------------------------
// Kernel 1: gather + L2-normalize + split to bf16 hi/lo. 1 row/wave (measured:
// G+launch ~= 25 us, r10 probe). Lane l owns channels l and l+64.
__global__ __launch_bounds__(256) void gather_norm_kernel(
    const float* __restrict__ seg,
    const int* __restrict__ pb, const int* __restrict__ ph, const int* __restrict__ pw,
    const int* __restrict__ nb, const int* __restrict__ nh, const int* __restrict__ nw,
    __hip_bfloat16* __restrict__ hi, __hip_bfloat16* __restrict__ lo)
{
    const int wave = threadIdx.x >> 6;
    const int lane = threadIdx.x & 63;
    const int row  = blockIdx.x * 4 + wave;
    if (row >= N_ROWS) return;

    int b, h, w;
    if (row < N_POS) { b = pb[row]; h = ph[row]; w = pw[row]; }
    else { const int r = row - N_POS; b = nb[r]; h = nh[r]; w = nw[r]; }

    const size_t cs   = (size_t)HH * WW;
    const size_t base = (size_t)b * C_CH * cs + (size_t)h * WW + (size_t)w;

    const float v0 = seg[base + (size_t)lane * cs];
    const float v1 = seg[base + (size_t)(lane + 64) * cs];

    float ss = v0 * v0 + v1 * v1;
#pragma unroll
    for (int m = 1; m < 64; m <<= 1) ss += __shfl_xor(ss, m, 64);

    const float n  = fmaxf(sqrtf(ss), EPS_N);
    const float u0 = v0 / n;
    const float u1 = v1 / n;

    const __hip_bfloat16 h0 = __float2bfloat16(u0);
    const __hip_bfloat16 h1 = __float2bfloat16(u1);
    const __hip_bfloat16 l0 = __float2bfloat16(u0 - __bfloat162float(h0));
    const __hip_bfloat16 l1 = __float2bfloat16(u1 - __bfloat162float(h1));

    const size_t o = (size_t)row * C_CH + lane;
    hi[o]      = h0;  lo[o]      = l0;
    hi[o + 64] = h1;  lo[o + 64] = l1;
}

// ---------------------------------------------------------------------------
// Kernel 2: C[i][j] = dot(x_i, x_j) via 3-term split-bf16 MFMA, no LDS.
// ONE CHANGE vs the 84.8us source: the 8 B-fragment loads of each K-step are
// batched into bh[4]/bl[4] BEFORE the MFMA loop, so all 16 loads of a K-step
// are in flight together (measured r14: loads were ~356 cyc apart = fully
// serialized; MfmaUtil 14%). VGPR ~84 -> ~116, same <=128 occupancy bucket.
__global__ __launch_bounds__(256, 2) void sim_mfma_kernel(
    const __hip_bfloat16* __restrict__ hi_, const __hip_bfloat16* __restrict__ lo_,
    float* __restrict__ partial)
{
    const ushort* __restrict__ hi = (const ushort*)hi_;
    const ushort* __restrict__ lo = (const ushort*)lo_;

    const int bid = blockIdx.x;
    const int ib  = bid / NJB;          // 0..15
    const int jb  = bid % NJB;          // 0..79  (ids sharing jb are == mod 8 -> same XCD)
    const int t    = threadIdx.x;
    const int wave = t >> 6;
    const int lane = t & 63;
    const int wy = wave >> 1;           // i-half
    const int wx = wave & 1;            // j-half

    const int iw0 = ib * 128 + wy * 64;
    const int jw0 = jb * 128 + wx * 64;

    const int lr = lane & 15;           // row/col within 16x16 tile
    const int lk = lane >> 4;           // k-chunk (8 bf16)

    f32x4 acc[4][4];
#pragma unroll
    for (int m = 0; m < 4; ++m)
#pragma unroll
        for (int n = 0; n < 4; ++n) acc[m][n] = (f32x4){0.f, 0.f, 0.f, 0.f};

#pragma unroll
    for (int ks = 0; ks < 4; ++ks) {
        const int koff = ks * 32 + lk * 8;

        bf16x8 ah[4], al[4], bh[4], bl[4];
#pragma unroll
        for (int m = 0; m < 4; ++m) {
            const size_t ra = (size_t)(iw0 + m * 16 + lr) * C_CH + koff;
            ah[m] = *(const bf16x8*)&hi[ra];
            al[m] = *(const bf16x8*)&lo[ra];
        }
#pragma unroll
        for (int n = 0; n < 4; ++n) {
            const size_t rb = (size_t)(jw0 + n * 16 + lr) * C_CH + koff;
            bh[n] = *(const bf16x8*)&hi[rb];
            bl[n] = *(const bf16x8*)&lo[rb];
        }

#pragma unroll
        for (int n = 0; n < 4; ++n) {
#pragma unroll
            for (int m = 0; m < 4; ++m) {
                acc[m][n] = __builtin_amdgcn_mfma_f32_16x16x32_bf16(ah[m], bh[n], acc[m][n], 0, 0, 0);
                acc[m][n] = __builtin_amdgcn_mfma_f32_16x16x32_bf16(ah[m], bl[n], acc[m][n], 0, 0, 0);
                acc[m][n] = __builtin_amdgcn_mfma_f32_16x16x32_bf16(al[m], bh[n], acc[m][n], 0, 0, 0);
            }
        }
    }

    // Epilogue. C/D layout: value r of lane l = C[iw0+m*16+(l>>4)*4+r][jw0+n*16+(l&15)]
    const int jslab = jw0 >> 6;         // 0..159
#pragma unroll
    for (int m = 0; m < 4; ++m) {
        float s0 = 0.f, s1 = 0.f, s2 = 0.f, s3 = 0.f;
#pragma unroll
        for (int n = 0; n < 4; ++n) {
            s0 += expf(acc[m][n][0]);
            s1 += expf(acc[m][n][1]);
            s2 += expf(acc[m][n][2]);
            s3 += expf(acc[m][n][3]);
        }
        float s[4] = {s0, s1, s2, s3};
#pragma unroll
        for (int r = 0; r < 4; ++r) {
            float v = s[r];
            v += __shfl_xor(v, 1, 64);
            v += __shfl_xor(v, 2, 64);
            v += __shfl_xor(v, 4, 64);
            v += __shfl_xor(v, 8, 64);
            if (lr == 0) {
                const int row = iw0 + m * 16 + lk * 4 + r;
                partial[(size_t)jslab * N_POS + row] = v;
            }
        }
    }
}

// ---------------------------------------------------------------------------
// Kernel 3a: per-row reduction + in-block sum (r11 form, measured fast).
__global__ __launch_bounds__(256) void rowred_kernel(
    const float* __restrict__ partial, float* __restrict__ bsum)
{
    const int t   = threadIdx.x;
    const int row = blockIdx.x * 256 + t;

    float P = 0.f;
#pragma unroll
    for (int s = 0; s < NJSLAB_POS; ++s) P += partial[(size_t)s * N_POS + row];

    float a0 = 0.f, a1 = 0.f, a2 = 0.f, a3 = 0.f;
    for (int s0 = NJSLAB_POS; s0 < NJSLAB; s0 += 16) {
        float v[16];
#pragma unroll
        for (int i = 0; i < 16; ++i)
            v[i] = partial[(size_t)(s0 + i) * N_POS + row];
#pragma unroll
        for (int i = 0; i < 16; i += 4) {
            a0 += v[i]; a1 += v[i + 1]; a2 += v[i + 2]; a3 += v[i + 3];
        }
    }
    const float Nv = (a0 + a1) + (a2 + a3);

    const float p = P - 2.71828182845904523536f;   // remove self-sim exp(1)
    const float term = logf(p) - logf(p + Nv);

    __shared__ float red[256];
    red[t] = term;
    __syncthreads();
    for (int s = 128; s > 0; s >>= 1) {
        if (t < s) red[t] += red[t + s];
        __syncthreads();
    }
    if (t == 0) bsum[blockIdx.x] = red[0];
}

// Kernel 3b: sum the 8 block sums. Single wave, deterministic.
__global__ __launch_bounds__(64) void final_kernel(
    const float* __restrict__ bsum, float* __restrict__ out)
{
    if (threadIdx.x == 0) {
        float s = 0.f;
#pragma unroll
        for (int i = 0; i < N_POS / 256; ++i) s += bsum[i];
        out[0] = -s / (float)N_POS;
    }
}

// ---------------------------------------------------------------------------
extern "C" void kernel_launch(void* const* d_in, const int* in_sizes, int n_in,
                              void* d_out, int out_size, void* d_ws, size_t ws_size,
                              hipStream_t stream)
{
    const float* seg = (const float*)d_in[0];
    const int* pb = (const int*)d_in[1];
    const int* ph = (const int*)d_in[2];
    const int* pw = (const int*)d_in[3];
    const int* nb = (const int*)d_in[4];
    const int* nh = (const int*)d_in[5];
    const int* nw = (const int*)d_in[6];
    float* out = (float*)d_out;

    __hip_bfloat16* hi = (__hip_bfloat16*)d_ws;
    __hip_bfloat16* lo = hi + (size_t)N_ROWS * C_CH;
    float* partial = (float*)(lo + (size_t)N_ROWS * C_CH);
    float* bsum    = partial + (size_t)NJSLAB * N_POS;

    gather_norm_kernel<<<dim3((N_ROWS + 3) / 4), dim3(256), 0, stream>>>(
        seg, pb, ph, pw, nb, nh, nw, hi, lo);

    sim_mfma_kernel<<<dim3(NIB * NJB), dim3(256), 0, stream>>>(hi, lo, partial);

    rowred_kernel<<<dim3(N_POS / 256), dim3(256), 0, stream>>>(partial, bsum);
    final_kernel<<<dim3(1), dim3(64), 0, stream>>>(bsum, out);
}

// Round 16
// 83.256 us; speedup vs baseline: 4.4260x; 1.0053x over previous
//
#include <hip/hip_runtime.h>
#include <hip/hip_bf16.h>
#include <math.h>

// Problem constants (match reference)
#define BB      8
#define C_CH    128
#define HH      256
#define WW      256
#define N_POS   2048
#define N_NEG   8192
#define N_ROWS  (N_POS + N_NEG)     // 10240
#define EPS_N   1e-6f

// sim tiling: ONE WAVE PER BLOCK (64 threads), each wave a 64x64 output tile.
// Grid = 32 i-tiles x 160 j-slabs = 5120 blocks. Wave-granular allocation ->
// more resident waves/CU than the old 4-wave blocks (r14: only 8 waves/CU).
#define NI2     (N_POS / 64)        // 32
#define NJS     (N_ROWS / 64)       // 160
#define NJSLAB      (N_ROWS / 64)   // 160
#define NJSLAB_POS  (N_POS / 64)    // 32

typedef __attribute__((ext_vector_type(8))) short bf16x8;   // 8 bf16 = 4 VGPR
typedef __attribute__((ext_vector_type(4))) float f32x4;    // MFMA C/D

// Workspace layout:
//   hi:      [N_ROWS][128] bf16   @ 0              (2.62 MB)
//   lo:      [N_ROWS][128] bf16   @ 2.62 MB        (2.62 MB)
//   partial: [NJSLAB][N_POS] f32                   (1.31 MB)
//   bsum:    [8] f32                               (32 B)

// ---------------------------------------------------------------------------
// Kernel 1: gather + L2-normalize + split to bf16 hi/lo. 1 row/wave (measured:
// G+launch ~= 25 us, r10 probe). Lane l owns channels l and l+64.
__global__ __launch_bounds__(256) void gather_norm_kernel(
    const float* __restrict__ seg,
    const int* __restrict__ pb, const int* __restrict__ ph, const int* __restrict__ pw,
    const int* __restrict__ nb, const int* __restrict__ nh, const int* __restrict__ nw,
    __hip_bfloat16* __restrict__ hi, __hip_bfloat16* __restrict__ lo)
{
    const int wave = threadIdx.x >> 6;
    const int lane = threadIdx.x & 63;
    const int row  = blockIdx.x * 4 + wave;
    if (row >= N_ROWS) return;

    int b, h, w;
    if (row < N_POS) { b = pb[row]; h = ph[row]; w = pw[row]; }
    else { const int r = row - N_POS; b = nb[r]; h = nh[r]; w = nw[r]; }

    const size_t cs   = (size_t)HH * WW;
    const size_t base = (size_t)b * C_CH * cs + (size_t)h * WW + (size_t)w;

    const float v0 = seg[base + (size_t)lane * cs];
    const float v1 = seg[base + (size_t)(lane + 64) * cs];

    float ss = v0 * v0 + v1 * v1;
#pragma unroll
    for (int m = 1; m < 64; m <<= 1) ss += __shfl_xor(ss, m, 64);

    const float n  = fmaxf(sqrtf(ss), EPS_N);
    const float u0 = v0 / n;
    const float u1 = v1 / n;

    const __hip_bfloat16 h0 = __float2bfloat16(u0);
    const __hip_bfloat16 h1 = __float2bfloat16(u1);
    const __hip_bfloat16 l0 = __float2bfloat16(u0 - __bfloat162float(h0));
    const __hip_bfloat16 l1 = __float2bfloat16(u1 - __bfloat162float(h1));

    const size_t o = (size_t)row * C_CH + lane;
    hi[o]      = h0;  lo[o]      = l0;
    hi[o + 64] = h1;  lo[o + 64] = l1;
}

// ---------------------------------------------------------------------------
// Kernel 2: C[i][j] = dot(x_i, x_j) via 3-term split-bf16 MFMA, no LDS.
// ONE CHANGE vs r15 (83.7us): 64-thread (1-wave) blocks. Same 64x64 tile,
// same batched loads. Blocks sharing a B-panel (same js) are == mod 8 ->
// same XCD L2.
__global__ __launch_bounds__(64) void sim_mfma_kernel(
    const __hip_bfloat16* __restrict__ hi_, const __hip_bfloat16* __restrict__ lo_,
    float* __restrict__ partial)
{
    const ushort* __restrict__ hi = (const ushort*)hi_;
    const ushort* __restrict__ lo = (const ushort*)lo_;

    const int bid = blockIdx.x;
    const int it  = bid / NJS;          // 0..31  (i-tile)
    const int js  = bid % NJS;          // 0..159 (j-slab; ids sharing js == mod 8 -> same XCD)
    const int lane = threadIdx.x & 63;

    const int iw0 = it * 64;
    const int jw0 = js * 64;

    const int lr = lane & 15;           // row/col within 16x16 tile
    const int lk = lane >> 4;           // k-chunk (8 bf16)

    f32x4 acc[4][4];
#pragma unroll
    for (int m = 0; m < 4; ++m)
#pragma unroll
        for (int n = 0; n < 4; ++n) acc[m][n] = (f32x4){0.f, 0.f, 0.f, 0.f};

#pragma unroll
    for (int ks = 0; ks < 4; ++ks) {
        const int koff = ks * 32 + lk * 8;

        bf16x8 ah[4], al[4], bh[4], bl[4];
#pragma unroll
        for (int m = 0; m < 4; ++m) {
            const size_t ra = (size_t)(iw0 + m * 16 + lr) * C_CH + koff;
            ah[m] = *(const bf16x8*)&hi[ra];
            al[m] = *(const bf16x8*)&lo[ra];
        }
#pragma unroll
        for (int n = 0; n < 4; ++n) {
            const size_t rb = (size_t)(jw0 + n * 16 + lr) * C_CH + koff;
            bh[n] = *(const bf16x8*)&hi[rb];
            bl[n] = *(const bf16x8*)&lo[rb];
        }

#pragma unroll
        for (int n = 0; n < 4; ++n) {
#pragma unroll
            for (int m = 0; m < 4; ++m) {
                acc[m][n] = __builtin_amdgcn_mfma_f32_16x16x32_bf16(ah[m], bh[n], acc[m][n], 0, 0, 0);
                acc[m][n] = __builtin_amdgcn_mfma_f32_16x16x32_bf16(ah[m], bl[n], acc[m][n], 0, 0, 0);
                acc[m][n] = __builtin_amdgcn_mfma_f32_16x16x32_bf16(al[m], bh[n], acc[m][n], 0, 0, 0);
            }
        }
    }

    // Epilogue. C/D layout: value r of lane l = C[iw0+m*16+(l>>4)*4+r][jw0+n*16+(l&15)]
#pragma unroll
    for (int m = 0; m < 4; ++m) {
        float s0 = 0.f, s1 = 0.f, s2 = 0.f, s3 = 0.f;
#pragma unroll
        for (int n = 0; n < 4; ++n) {
            s0 += expf(acc[m][n][0]);
            s1 += expf(acc[m][n][1]);
            s2 += expf(acc[m][n][2]);
            s3 += expf(acc[m][n][3]);
        }
        float s[4] = {s0, s1, s2, s3};
#pragma unroll
        for (int r = 0; r < 4; ++r) {
            float v = s[r];
            v += __shfl_xor(v, 1, 64);
            v += __shfl_xor(v, 2, 64);
            v += __shfl_xor(v, 4, 64);
            v += __shfl_xor(v, 8, 64);
            if (lr == 0) {
                const int row = iw0 + m * 16 + lk * 4 + r;
                partial[(size_t)js * N_POS + row] = v;
            }
        }
    }
}

// ---------------------------------------------------------------------------
// Kernel 3a: per-row reduction + in-block sum (r11 form, measured fast).
__global__ __launch_bounds__(256) void rowred_kernel(
    const float* __restrict__ partial, float* __restrict__ bsum)
{
    const int t   = threadIdx.x;
    const int row = blockIdx.x * 256 + t;

    float P = 0.f;
#pragma unroll
    for (int s = 0; s < NJSLAB_POS; ++s) P += partial[(size_t)s * N_POS + row];

    float a0 = 0.f, a1 = 0.f, a2 = 0.f, a3 = 0.f;
    for (int s0 = NJSLAB_POS; s0 < NJSLAB; s0 += 16) {
        float v[16];
#pragma unroll
        for (int i = 0; i < 16; ++i)
            v[i] = partial[(size_t)(s0 + i) * N_POS + row];
#pragma unroll
        for (int i = 0; i < 16; i += 4) {
            a0 += v[i]; a1 += v[i + 1]; a2 += v[i + 2]; a3 += v[i + 3];
        }
    }
    const float Nv = (a0 + a1) + (a2 + a3);

    const float p = P - 2.71828182845904523536f;   // remove self-sim exp(1)
    const float term = logf(p) - logf(p + Nv);

    __shared__ float red[256];
    red[t] = term;
    __syncthreads();
    for (int s = 128; s > 0; s >>= 1) {
        if (t < s) red[t] += red[t + s];
        __syncthreads();
    }
    if (t == 0) bsum[blockIdx.x] = red[0];
}

// Kernel 3b: sum the 8 block sums. Single wave, deterministic.
__global__ __launch_bounds__(64) void final_kernel(
    const float* __restrict__ bsum, float* __restrict__ out)
{
    if (threadIdx.x == 0) {
        float s = 0.f;
#pragma unroll
        for (int i = 0; i < N_POS / 256; ++i) s += bsum[i];
        out[0] = -s / (float)N_POS;
    }
}

// ---------------------------------------------------------------------------
extern "C" void kernel_launch(void* const* d_in, const int* in_sizes, int n_in,
                              void* d_out, int out_size, void* d_ws, size_t ws_size,
                              hipStream_t stream)
{
    const float* seg = (const float*)d_in[0];
    const int* pb = (const int*)d_in[1];
    const int* ph = (const int*)d_in[2];
    const int* pw = (const int*)d_in[3];
    const int* nb = (const int*)d_in[4];
    const int* nh = (const int*)d_in[5];
    const int* nw = (const int*)d_in[6];
    float* out = (float*)d_out;

    __hip_bfloat16* hi = (__hip_bfloat16*)d_ws;
    __hip_bfloat16* lo = hi + (size_t)N_ROWS * C_CH;
    float* partial = (float*)(lo + (size_t)N_ROWS * C_CH);
    float* bsum    = partial + (size_t)NJSLAB * N_POS;

    gather_norm_kernel<<<dim3((N_ROWS + 3) / 4), dim3(256), 0, stream>>>(
        seg, pb, ph, pw, nb, nh, nw, hi, lo);

    sim_mfma_kernel<<<dim3(NI2 * NJS), dim3(64), 0, stream>>>(hi, lo, partial);

    rowred_kernel<<<dim3(N_POS / 256), dim3(256), 0, stream>>>(partial, bsum);
    final_kernel<<<dim3(1), dim3(64), 0, stream>>>(bsum, out);
}

// Round 17
// 66.695 us; speedup vs baseline: 5.5250x; 1.2483x over previous
//
#include <hip/hip_runtime.h>
#include <hip/hip_bf16.h>
#include <math.h>

// Problem constants (match reference)
#define BB      8
#define C_CH    128
#define HH      256
#define WW      256
#define N_POS   2048
#define N_NEG   8192
#define N_ROWS  (N_POS + N_NEG)     // 10240
#define EPS_N   1e-6f

// sim tiling: 1-wave blocks (r16 form), each wave a 64x64 output tile.
#define NI2     (N_POS / 64)        // 32
#define NJS     (N_ROWS / 64)       // 160
#define NJSLAB      (N_ROWS / 64)   // 160
#define NJSLAB_POS  (N_POS / 64)    // 32

// Fragment-swizzled operand layout (THE change this round):
//   buffer[tile][ks][lane][8]  shorts, tile=row/16 (640), ks=k/32 (4),
//   lane = (k%32)/8*16 + row%16  (0..63), elem = k%8.
// A fragment load for (tile,ks) = lane l reads base + l*8 shorts -> the wave
// reads 1KB CONTIGUOUS (8 x 128B lines) instead of 16 scattered 64B segments
// (r14 counters: memory pipe saturated at ~5.5 cyc/line, MfmaUtil 14%).
#define PANEL   512                  // shorts per (tile,ks) panel: 64 lanes x 8

typedef __attribute__((ext_vector_type(8))) short bf16x8;   // 8 bf16 = 4 VGPR
typedef __attribute__((ext_vector_type(4))) float f32x4;    // MFMA C/D

// Workspace layout:
//   hi_t:    [640][4][64][8] bf16  @ 0              (2.62 MB)
//   lo_t:    same                                    (2.62 MB)
//   partial: [NJSLAB][N_POS] f32                     (1.31 MB)
//   bsum:    [8] f32

// ---------------------------------------------------------------------------
// Kernel 1: gather + L2-normalize + split to bf16 hi/lo, writing the
// fragment-swizzled layout. 1 row/wave. Lane l owns channels l and l+64.
__global__ __launch_bounds__(256) void gather_norm_kernel(
    const float* __restrict__ seg,
    const int* __restrict__ pb, const int* __restrict__ ph, const int* __restrict__ pw,
    const int* __restrict__ nb, const int* __restrict__ nh, const int* __restrict__ nw,
    ushort* __restrict__ hi_t, ushort* __restrict__ lo_t)
{
    const int wave = threadIdx.x >> 6;
    const int lane = threadIdx.x & 63;
    const int row  = blockIdx.x * 4 + wave;
    if (row >= N_ROWS) return;

    int b, h, w;
    if (row < N_POS) { b = pb[row]; h = ph[row]; w = pw[row]; }
    else { const int r = row - N_POS; b = nb[r]; h = nh[r]; w = nw[r]; }

    const size_t cs   = (size_t)HH * WW;
    const size_t base = (size_t)b * C_CH * cs + (size_t)h * WW + (size_t)w;

    const float v0 = seg[base + (size_t)lane * cs];
    const float v1 = seg[base + (size_t)(lane + 64) * cs];

    float ss = v0 * v0 + v1 * v1;
#pragma unroll
    for (int m = 1; m < 64; m <<= 1) ss += __shfl_xor(ss, m, 64);

    const float n  = fmaxf(sqrtf(ss), EPS_N);
    const float u0 = v0 / n;
    const float u1 = v1 / n;

    const __hip_bfloat16 h0 = __float2bfloat16(u0);
    const __hip_bfloat16 h1 = __float2bfloat16(u1);
    const __hip_bfloat16 l0 = __float2bfloat16(u0 - __bfloat162float(h0));
    const __hip_bfloat16 l1 = __float2bfloat16(u1 - __bfloat162float(h1));

    // swizzled destinations for elements e0=lane, e1=lane+64 of row
    const int tile = row >> 4;
    const int lr   = row & 15;

    const int e0 = lane;
    const int ks0 = e0 >> 5, lk0 = (e0 & 31) >> 3, ke0 = e0 & 7;
    const size_t o0 = ((size_t)(tile * 4 + ks0) * 64 + lk0 * 16 + lr) * 8 + ke0;

    const int e1 = lane + 64;
    const int ks1 = e1 >> 5, lk1 = (e1 & 31) >> 3, ke1 = e1 & 7;
    const size_t o1 = ((size_t)(tile * 4 + ks1) * 64 + lk1 * 16 + lr) * 8 + ke1;

    hi_t[o0] = __hip_bfloat16_raw(h0).x;  lo_t[o0] = __hip_bfloat16_raw(l0).x;
    hi_t[o1] = __hip_bfloat16_raw(h1).x;  lo_t[o1] = __hip_bfloat16_raw(l1).x;
}

// ---------------------------------------------------------------------------
// Kernel 2: C[i][j] = dot(x_i, x_j) via 3-term split-bf16 MFMA, no LDS.
// Fragment loads are now CONTIGUOUS (1KB/wave/load) from the swizzled layout.
// Structure otherwise identical to r16 (1-wave blocks, batched loads).
__global__ __launch_bounds__(64) void sim_mfma_kernel(
    const ushort* __restrict__ hi_t, const ushort* __restrict__ lo_t,
    float* __restrict__ partial)
{
    const int bid = blockIdx.x;
    const int it  = bid / NJS;          // 0..31  (i-tile of 64 rows)
    const int js  = bid % NJS;          // 0..159 (j-slab; ids sharing js == mod 8 -> same XCD)
    const int lane = threadIdx.x & 63;

    const int iw0 = it * 64;

    const int lr = lane & 15;
    const int lk = lane >> 4;

    f32x4 acc[4][4];
#pragma unroll
    for (int m = 0; m < 4; ++m)
#pragma unroll
        for (int n = 0; n < 4; ++n) acc[m][n] = (f32x4){0.f, 0.f, 0.f, 0.f};

#pragma unroll
    for (int ks = 0; ks < 4; ++ks) {
        bf16x8 ah[4], al[4], bh[4], bl[4];
#pragma unroll
        for (int m = 0; m < 4; ++m) {
            const size_t pa = ((size_t)((it * 4 + m) * 4 + ks)) * PANEL + lane * 8;
            ah[m] = *(const bf16x8*)&hi_t[pa];
            al[m] = *(const bf16x8*)&lo_t[pa];
        }
#pragma unroll
        for (int n = 0; n < 4; ++n) {
            const size_t pb2 = ((size_t)((js * 4 + n) * 4 + ks)) * PANEL + lane * 8;
            bh[n] = *(const bf16x8*)&hi_t[pb2];
            bl[n] = *(const bf16x8*)&lo_t[pb2];
        }

#pragma unroll
        for (int n = 0; n < 4; ++n) {
#pragma unroll
            for (int m = 0; m < 4; ++m) {
                acc[m][n] = __builtin_amdgcn_mfma_f32_16x16x32_bf16(ah[m], bh[n], acc[m][n], 0, 0, 0);
                acc[m][n] = __builtin_amdgcn_mfma_f32_16x16x32_bf16(ah[m], bl[n], acc[m][n], 0, 0, 0);
                acc[m][n] = __builtin_amdgcn_mfma_f32_16x16x32_bf16(al[m], bh[n], acc[m][n], 0, 0, 0);
            }
        }
    }

    // Epilogue. C/D layout: value r of lane l = C[iw0+m*16+(l>>4)*4+r][jw0+n*16+(l&15)]
#pragma unroll
    for (int m = 0; m < 4; ++m) {
        float s0 = 0.f, s1 = 0.f, s2 = 0.f, s3 = 0.f;
#pragma unroll
        for (int n = 0; n < 4; ++n) {
            s0 += expf(acc[m][n][0]);
            s1 += expf(acc[m][n][1]);
            s2 += expf(acc[m][n][2]);
            s3 += expf(acc[m][n][3]);
        }
        float s[4] = {s0, s1, s2, s3};
#pragma unroll
        for (int r = 0; r < 4; ++r) {
            float v = s[r];
            v += __shfl_xor(v, 1, 64);
            v += __shfl_xor(v, 2, 64);
            v += __shfl_xor(v, 4, 64);
            v += __shfl_xor(v, 8, 64);
            if (lr == 0) {
                const int row = iw0 + m * 16 + lk * 4 + r;
                partial[(size_t)js * N_POS + row] = v;
            }
        }
    }
}

// ---------------------------------------------------------------------------
// Kernel 3a: per-row reduction + in-block sum (r11 form, measured fast).
__global__ __launch_bounds__(256) void rowred_kernel(
    const float* __restrict__ partial, float* __restrict__ bsum)
{
    const int t   = threadIdx.x;
    const int row = blockIdx.x * 256 + t;

    float P = 0.f;
#pragma unroll
    for (int s = 0; s < NJSLAB_POS; ++s) P += partial[(size_t)s * N_POS + row];

    float a0 = 0.f, a1 = 0.f, a2 = 0.f, a3 = 0.f;
    for (int s0 = NJSLAB_POS; s0 < NJSLAB; s0 += 16) {
        float v[16];
#pragma unroll
        for (int i = 0; i < 16; ++i)
            v[i] = partial[(size_t)(s0 + i) * N_POS + row];
#pragma unroll
        for (int i = 0; i < 16; i += 4) {
            a0 += v[i]; a1 += v[i + 1]; a2 += v[i + 2]; a3 += v[i + 3];
        }
    }
    const float Nv = (a0 + a1) + (a2 + a3);

    const float p = P - 2.71828182845904523536f;   // remove self-sim exp(1)
    const float term = logf(p) - logf(p + Nv);

    __shared__ float red[256];
    red[t] = term;
    __syncthreads();
    for (int s = 128; s > 0; s >>= 1) {
        if (t < s) red[t] += red[t + s];
        __syncthreads();
    }
    if (t == 0) bsum[blockIdx.x] = red[0];
}

// Kernel 3b: sum the 8 block sums. Single wave, deterministic.
__global__ __launch_bounds__(64) void final_kernel(
    const float* __restrict__ bsum, float* __restrict__ out)
{
    if (threadIdx.x == 0) {
        float s = 0.f;
#pragma unroll
        for (int i = 0; i < N_POS / 256; ++i) s += bsum[i];
        out[0] = -s / (float)N_POS;
    }
}

// ---------------------------------------------------------------------------
extern "C" void kernel_launch(void* const* d_in, const int* in_sizes, int n_in,
                              void* d_out, int out_size, void* d_ws, size_t ws_size,
                              hipStream_t stream)
{
    const float* seg = (const float*)d_in[0];
    const int* pb = (const int*)d_in[1];
    const int* ph = (const int*)d_in[2];
    const int* pw = (const int*)d_in[3];
    const int* nb = (const int*)d_in[4];
    const int* nh = (const int*)d_in[5];
    const int* nw = (const int*)d_in[6];
    float* out = (float*)d_out;

    ushort* hi_t = (ushort*)d_ws;
    ushort* lo_t = hi_t + (size_t)N_ROWS * C_CH;
    float* partial = (float*)(lo_t + (size_t)N_ROWS * C_CH);
    float* bsum    = partial + (size_t)NJSLAB * N_POS;

    gather_norm_kernel<<<dim3((N_ROWS + 3) / 4), dim3(256), 0, stream>>>(
        seg, pb, ph, pw, nb, nh, nw, hi_t, lo_t);

    sim_mfma_kernel<<<dim3(NI2 * NJS), dim3(64), 0, stream>>>(hi_t, lo_t, partial);

    rowred_kernel<<<dim3(N_POS / 256), dim3(256), 0, stream>>>(partial, bsum);
    final_kernel<<<dim3(1), dim3(64), 0, stream>>>(bsum, out);
}